// Round 8
// baseline (126.659 us; speedup 1.0000x reference)
//
#include <hip/hip_runtime.h>
#include <stdint.h>

#define Bn   8
#define CIN  64
#define Hh   128
#define Wh   128
#define COUT 64
#define Tt   9
#define HO   128
#define WO   128
#define HW   (HO * WO)

// Block tile = 8 rows x 16 cols of output pixels (128 px, 4 waves x 32 px,
// 32x32x16 MFMA). Staged region: halo_y=3, halo_x=4 -> 15 x 25 records at
// 144-B stride (bank sweep, immediate-offset ds_read_b128). 54,000 B LDS ->
// 3 blocks/CU (R7 was 61,200 B -> 2 blocks/CU; R7 analysis: LDS pipe only
// ~50% utilized -> latency-underutilized, so buy residency with halo_y).
#define RH     15
#define RWC    25
#define RREC   (RH * RWC)    // 375
#define RSTR   144           // record stride bytes
#define HALO_Y 3
#define HALO_X 4

typedef _Float16 h16;
typedef __attribute__((ext_vector_type(2)))  _Float16 h2;
typedef __attribute__((ext_vector_type(8)))  _Float16 h8;
typedef __attribute__((ext_vector_type(16))) float    f16v;

// Module-scope scratch (NOT d_ws: R1 overflowed ws_size and corrupted the
// harness's pristine inputs). 16 MiB fp16 NHWC x + 72 KiB fp16 weights.
__device__ h16 g_xT[(size_t)Bn * Hh * Wh * CIN];
__device__ h16 g_wh[Tt * 4 * 2 * 64 * 8];   // [t][ks][mt][lane][j]

// ---------------------------------------------------------------------------
// prep: blocks [0,1024) transpose x NCHW fp32 -> g_xT NHWC fp16 (block per
// (b,y)); blocks [1024,1168) repack weight -> fp16 32x32x16 A-frag order:
// a(t,ks,mt)[lane][j] = W[o = mt*32 + (lane&31)][c = ks*16 + (lane>>5)*8 + j]
// ---------------------------------------------------------------------------
__global__ __launch_bounds__(256) void prep(const float* __restrict__ x,
                                            const float* __restrict__ w) {
    if (blockIdx.x >= Bn * Hh) {
        int tid = (blockIdx.x - Bn * Hh) * 256 + threadIdx.x;   // 36864
        int t   = tid >> 12;
        int rem = tid & 4095;
        int ks  = rem >> 10;
        int mt  = (rem >> 9) & 1;
        int ln  = (rem >> 3) & 63;
        int j   = rem & 7;
        int o   = mt * 32 + (ln & 31);
        int c   = ks * 16 + ((ln >> 5) << 3) + j;
        g_wh[tid] = (h16)w[(size_t)(o * 64 + c) * 9 + t];
        return;
    }
    int b = blockIdx.x >> 7;
    int y = blockIdx.x & 127;
    __shared__ uint32_t tile[64][65];   // [c][x/2] packed fp16 pair

    const float* src = x + ((size_t)b * CIN) * (Hh * Wh) + (size_t)y * Wh;
    int t    = threadIdx.x;
    int xp   = t & 63;     // x-pair
    int csub = t >> 6;     // 0..3
    #pragma unroll
    for (int cc = 0; cc < 64; cc += 4) {
        int c = cc + csub;
        float2 v = *(const float2*)(src + (size_t)c * (Hh * Wh) + xp * 2);
        uint32_t h0 = (uint32_t)__builtin_bit_cast(uint16_t, (h16)v.x);
        uint32_t h1 = (uint32_t)__builtin_bit_cast(uint16_t, (h16)v.y);
        tile[c][xp] = h0 | (h1 << 16);
    }
    __syncthreads();

    uint32_t* dst = (uint32_t*)(g_xT + (((size_t)b * Hh + y) * Wh) * CIN);
    int d  = t & 31;
    int xo = t >> 5;
    #pragma unroll
    for (int it = 0; it < 16; ++it) {
        int xg = it * 8 + xo;
        uint32_t lo = tile[2 * d][xg >> 1];
        uint32_t hi = tile[2 * d + 1][xg >> 1];
        int sh = (xg & 1) * 16;
        uint32_t l0 = (lo >> sh) & 0xffffu;
        uint32_t h1 = (hi >> sh) & 0xffffu;
        dst[xg * 32 + d] = l0 | (h1 << 16);
    }
}

// ---------------------------------------------------------------------------
// dcn_main: 1024 blocks x 4 waves; wave owns 2 rows x 16 cols (32 px) x all
// 64 COUT via 2x v_mfma_f32_32x32x16_f16 per (tap,ks). Region in LDS at
// 144-B record stride; 3 blocks/CU. Fallback (offset beyond halo, ~40% of
// wave-taps but ~1-2 lanes each) reads global. b = blk&7: XCD-affine L2.
// ---------------------------------------------------------------------------
__global__ __launch_bounds__(256) void dcn_main(
        const float* __restrict__ offset, const float* __restrict__ mask,
        const float* __restrict__ bias, float* __restrict__ out) {
    __shared__ __align__(16) uint8_t sreg[RREC * RSTR];   // 54,000 B

    int blk  = blockIdx.x;
    int b    = blk & 7;
    int s    = blk >> 3;            // tile id within batch, 128 tiles
    int ty   = s >> 3, tx = s & 7;
    int i0   = ty * 8, j0 = tx * 16;
    int lane = threadIdx.x & 63;
    int wave = threadIdx.x >> 6;
    int n    = lane & 31;           // pixel within wave
    int g    = lane >> 5;           // channel group (8 ch)

    const h16* xb = g_xT + (size_t)b * (Hh * Wh * CIN);

    int i = i0 + 2 * wave + (n >> 4);
    int j = j0 + (n & 15);
    int p = (i << 7) + j;

    // Hoisted: independent of staging, overlaps its latency.
    const float* offB = offset + (size_t)b * (2 * Tt * HW);
    const float* mskB = mask   + (size_t)b * (Tt * HW);
    float dyv[Tt], dxv[Tt], mmv[Tt];
    #pragma unroll
    for (int t = 0; t < Tt; ++t) {
        dyv[t] = offB[(2 * t) * HW + p];
        dxv[t] = offB[(2 * t + 1) * HW + p];
        mmv[t] = mskB[t * HW + p];
    }

    // ---- stage region: 375 records x 8 quads = 3000 uint4 ----
    {
        const int base_y = i0 - HALO_Y, base_x = j0 - HALO_X;
        #pragma unroll
        for (int it = 0; it < 12; ++it) {
            int idx  = it * 256 + threadIdx.x;
            int rec  = idx >> 3;
            int quad = idx & 7;
            if (rec < RREC) {
                int ry = rec / RWC, rx = rec - ry * RWC;
                int gy = min(max(base_y + ry, 0), Hh - 1);
                int gx = min(max(base_x + rx, 0), Wh - 1);
                uint4 v = *(const uint4*)(xb + ((gy << 7) + gx) * 64 + quad * 8);
                *(uint4*)(sreg + rec * RSTR + quad * 16) = v;
            }
        }
    }
    __syncthreads();

    f16v acc[2] = {};

    #pragma unroll
    for (int t = 0; t < Tt; ++t) {
        const int ky = t / 3, kx = t % 3;
        float py = dyv[t] + (float)(i + ky - 1);
        float px = dxv[t] + (float)(j + kx - 1);
        float fy = floorf(py), fx = floorf(px);
        int   y0 = (int)fy,    x0 = (int)fx;
        float ly = py - fy,    lx = px - fx;
        float hy = 1.f - ly,   hx = 1.f - lx;
        // fold mask into the y-pair (each corner weight uses exactly one)
        float m = mmv[t];
        hy *= m; ly *= m;

        bool vy0 = (y0 >= 0) && (y0 < Hh);
        bool vy1 = (y0 >= -1) && (y0 < Hh - 1);
        bool vx0 = (x0 >= 0) && (x0 < Wh);
        bool vx1 = (x0 >= -1) && (x0 < Wh - 1);
        float w00 = (vy0 && vx0) ? hy * hx : 0.f;
        float w01 = (vy0 && vx1) ? hy * lx : 0.f;
        float w10 = (vy1 && vx0) ? ly * hx : 0.f;
        float w11 = (vy1 && vx1) ? ly * lx : 0.f;

        // region-local record coords; corner+1 needs ry<=RH-2, rx<=RWC-2
        int ry = y0 - i0 + HALO_Y;
        int rx = x0 - j0 + HALO_X;
        bool intile = (ry >= 0) & (ry <= RH - 2) & (rx >= 0) & (rx <= RWC - 2);
        int ryc = min(max(ry, 0), RH - 2), rxc = min(max(rx, 0), RWC - 2);
        int pl00 = ryc * RWC + rxc;
        // One per-tap base; 16 reads at uniform immediate offsets.
        const uint8_t* cbase = sreg + pl00 * RSTR + g * 16;

        union U4 { uint4 v; h2 h[4]; };
        U4 c00[4], c01[4], c10[4], c11[4];
        #pragma unroll
        for (int ks = 0; ks < 4; ++ks) {
            c00[ks].v = *(const uint4*)(cbase + ks * 32);
            c01[ks].v = *(const uint4*)(cbase + RSTR + ks * 32);
            c10[ks].v = *(const uint4*)(cbase + RWC * RSTR + ks * 32);
            c11[ks].v = *(const uint4*)(cbase + (RWC + 1) * RSTR + ks * 32);
        }
        if (__any(!intile)) {   // few-lane global fallback (offset beyond halo)
            if (!intile) {
                int y0c = min(max(y0, 0), Hh - 1), y1c = min(max(y0 + 1, 0), Hh - 1);
                int x0c = min(max(x0, 0), Wh - 1), x1c = min(max(x0 + 1, 0), Wh - 1);
                const h16* r0 = xb + (size_t)(y0c * Wh) * CIN;
                const h16* r1 = xb + (size_t)(y1c * Wh) * CIN;
                #pragma unroll
                for (int ks = 0; ks < 4; ++ks) {
                    int c = ks * 16 + g * 8;
                    c00[ks].v = *(const uint4*)(r0 + x0c * CIN + c);
                    c01[ks].v = *(const uint4*)(r0 + x1c * CIN + c);
                    c10[ks].v = *(const uint4*)(r1 + x0c * CIN + c);
                    c11[ks].v = *(const uint4*)(r1 + x1c * CIN + c);
                }
            }
        }

        h2 W00 = {(h16)w00, (h16)w00};
        h2 W01 = {(h16)w01, (h16)w01};
        h2 W10 = {(h16)w10, (h16)w10};
        h2 W11 = {(h16)w11, (h16)w11};

        const h16* wt = g_wh + t * 4096;
        #pragma unroll
        for (int ks = 0; ks < 4; ++ks) {
            union { h2 r[4]; h8 v; } pk;
            #pragma unroll
            for (int e = 0; e < 4; ++e) {
                h2 r = c00[ks].h[e] * W00;
                r = c01[ks].h[e] * W01 + r;
                r = c10[ks].h[e] * W10 + r;
                r = c11[ks].h[e] * W11 + r;
                pk.r[e] = r;
            }
            #pragma unroll
            for (int mt = 0; mt < 2; ++mt) {
                h8 a = *(const h8*)(wt + (ks * 2 + mt) * 512 + lane * 8);
                acc[mt] = __builtin_amdgcn_mfma_f32_32x32x16_f16(
                    a, pk.v, acc[mt], 0, 0, 0);
            }
        }
    }

    // C/D layout (32x32): col = lane&31 (= px), row = (r&3) + 8*(r>>2) + 4*g.
    #pragma unroll
    for (int mt = 0; mt < 2; ++mt) {
        #pragma unroll
        for (int r = 0; r < 16; ++r) {
            int o = mt * 32 + (r & 3) + 8 * (r >> 2) + 4 * g;
            out[(size_t)(b * COUT + o) * HW + p] = acc[mt][r] + bias[o];
        }
    }
}

extern "C" void kernel_launch(void* const* d_in, const int* in_sizes, int n_in,
                              void* d_out, int out_size, void* d_ws, size_t ws_size,
                              hipStream_t stream) {
    const float* x      = (const float*)d_in[0];
    const float* offset = (const float*)d_in[1];
    const float* mask   = (const float*)d_in[2];
    const float* weight = (const float*)d_in[3];
    const float* bias   = (const float*)d_in[4];
    (void)d_ws; (void)ws_size;

    prep<<<Bn * Hh + 144, 256, 0, stream>>>(x, weight);
    dcn_main<<<Bn * 128, 256, 0, stream>>>(offset, mask, bias, (float*)d_out);
}